// Round 14
// baseline (64.603 us; speedup 1.0000x reference)
//
#include <hip/hip_runtime.h>
#include <math.h>

// ---------------- ws layout (float indices) ----------------
#define W_MUP2  0                       // 1024: per-(n,c,q) quarter-plane sums
#define W_LOP   1024                    // 512 cos-min partials (n*128+bb)
#define W_HIP   2048                    // 512 cos-max partials
#define W_CMXP  3072                    // 512 co-max partials
#define W_O1T   3840                    // 144*128 transposed o1w
#define W_O2T   22272                   // 128*128 transposed o2w
#define W_COS   38912                   // 4*65536
#define W_GP    (W_COS + 262144)        // 512 blocks * 256 gram partials
#define W_RAW   (W_GP + 131072)         // 4 * [pos(256)][ch(128)] o1 pre-BN (TRANSPOSED)
#define W_BN1P  (W_RAW + 131072)        // [row(256)][block(256)]: rows 0-127 = S(ch), 128-255 = S2(ch)
#define W_BN2P  (W_BN1P + 65536)        // [row(256)][block(256)]: rows 0-127 = A(ch), 128-255 = S2(ch)

// ---------------- wave-64 reductions ----------------
__device__ __forceinline__ float wrSum(float v){
#pragma unroll
  for(int o = 32; o > 0; o >>= 1) v += __shfl_down(v, o, 64);
  return v;
}
__device__ __forceinline__ float wrSumX(float v){
#pragma unroll
  for(int o = 32; o > 0; o >>= 1) v += __shfl_xor(v, o, 64);
  return v;
}
__device__ __forceinline__ float wrMax(float v){
#pragma unroll
  for(int o = 32; o > 0; o >>= 1) v = fmaxf(v, __shfl_down(v, o, 64));
  return v;
}
__device__ __forceinline__ float wrMin(float v){
#pragma unroll
  for(int o = 32; o > 0; o >>= 1) v = fminf(v, __shfl_down(v, o, 64));
  return v;
}

// ================= K1: mu partials (x pass 1, 1024 blks) + weight transposes =================
__global__ __launch_bounds__(256)
void k_mu(const float* __restrict__ x, const float* __restrict__ o1w,
          const float* __restrict__ o2w, float* __restrict__ ws){
  const int t = threadIdx.x, b = blockIdx.x;
  if(b < 1024){
    __shared__ float red[4];
    const float4* xb = (const float4*)(x + b*4096);
    float4 v0 = xb[t], v1 = xb[t+256], v2 = xb[t+512], v3 = xb[t+768];
    float s = ((v0.x+v0.y)+(v0.z+v0.w)) + ((v1.x+v1.y)+(v1.z+v1.w))
            + ((v2.x+v2.y)+(v2.z+v2.w)) + ((v3.x+v3.y)+(v3.z+v3.w));
    s = wrSum(s);
    if((t & 63) == 0) red[t>>6] = s;
    __syncthreads();
    if(t == 0) ws[W_MUP2 + b] = (red[0]+red[1])+(red[2]+red[3]);
  } else if(b < 1042){
    const int c0 = (b - 1024)*8;
#pragma unroll
    for(int j = 0; j < 4; ++j){
      int idx = t + j*256;
      int ch = idx & 127, c = c0 + (idx >> 7);
      if(c < 144) ws[W_O1T + c*128 + ch] = o1w[ch*144 + c];
    }
  } else {
    const int c0 = (b - 1042)*8;
#pragma unroll
    for(int j = 0; j < 4; ++j){
      int idx = t + j*256;
      int ch = idx & 127, c = c0 + (idx >> 7);
      ws[W_O2T + c*128 + ch] = o2w[ch*128 + c];
    }
  }
}

// ================= K2: cos field (x pass 2, 512 blks, 2 px/thread float2) =================
__global__ __launch_bounds__(256)
void k_cos(const float* __restrict__ x, float* __restrict__ ws){
  __shared__ float sp[256];
  __shared__ float mu[16];
  __shared__ float red[8];
  const int t = threadIdx.x, b = blockIdx.x;
  const int n = b >> 7, bb = b & 127;
  sp[t] = ws[W_MUP2 + n*256 + t];
  __syncthreads();
  if(t < 16){
    float m = 0.0f;
#pragma unroll
    for(int q = 0; q < 16; ++q) m += sp[t*16 + q];
    mu[t] = m * (1.0f/65536.0f);
  }
  __syncthreads();
  float nn = 0.0f;
#pragma unroll
  for(int c = 0; c < 16; ++c) nn += mu[c]*mu[c];
  const float inv = 1.0f / fmaxf(sqrtf(nn), 1e-12f);
  const float2* xp = (const float2*)(x + n*1048576 + bb*512) + t;
  float dot0 = 0.0f, xx0 = 0.0f, dot1 = 0.0f, xx1 = 0.0f;
#pragma unroll
  for(int c = 0; c < 16; ++c){
    float2 v = xp[c*32768];
    dot0 += v.x*mu[c]; xx0 += v.x*v.x;
    dot1 += v.y*mu[c]; xx1 += v.y*v.y;
  }
  const float cv0 = dot0 * inv / fmaxf(sqrtf(xx0), 1e-12f);
  const float cv1 = dot1 * inv / fmaxf(sqrtf(xx1), 1e-12f);
  *(float2*)(ws + W_COS + n*65536 + bb*512 + 2*t) = make_float2(cv0, cv1);
  float lo = wrMin(fminf(cv0, cv1)), hi = wrMax(fmaxf(cv0, cv1));
  if((t & 63) == 0){ red[t>>6] = lo; red[4 + (t>>6)] = hi; }
  __syncthreads();
  if(t == 0){
    ws[W_LOP + n*128 + bb] = fminf(fminf(red[0],red[1]),fminf(red[2],red[3]));
    ws[W_HIP + n*128 + bb] = fmaxf(fmaxf(red[4],red[5]),fmaxf(red[6],red[7]));
  }
}

// ================= K3: quant + Gram partials + co-max partials (512 blks x 2 rows) ==========
__global__ __launch_bounds__(256) void k_gram(float* __restrict__ ws){
  __shared__ __align__(16) float smem[10256];
  float* Lsh = smem;            // 5120
  float* Rsh = smem + 5120;     // 5120
  const int t = threadIdx.x, b = blockIdx.x;
  const int n = b >> 7, h0 = (b & 127) << 1;       // 2 rows per block
  {
    float lo = (t < 128) ? ws[W_LOP + n*128 + t] : 1e30f;
    float hi = (t < 128) ? ws[W_HIP + n*128 + t] : -1e30f;
    lo = wrMin(lo); hi = wrMax(hi);
    if((t & 63) == 0){ smem[10240 + (t>>6)] = lo; smem[10244 + (t>>6)] = hi; }
  }
  __syncthreads();
  const float cmin = fminf(fminf(smem[10240],smem[10241]),fminf(smem[10242],smem[10243]));
  const float cmax = fmaxf(fmaxf(smem[10244],smem[10245]),fmaxf(smem[10246],smem[10247]));
  const float dqv  = cmax - cmin;
  float q[16];
#pragma unroll
  for(int l = 0; l < 16; ++l) q[l] = (float)(2*l+1) * (1.0f/32.0f) * dqv + cmin;

  const int m  = t & 15;
  const int g  = t >> 4;
  const int i0 = (m >> 2) << 2;
  const int j0 = (m & 3) << 2;
  float acc[4][4] = {{0.0f}};
  float mp = 0.0f;
  const float* cosp = ws + W_COS + n*65536;

  __syncthreads();
#pragma unroll
  for(int ch = 0; ch < 2; ++ch){
    const int h = h0 + ch;
    const float cl = cosp[h*256 + t];
    const bool valid = (h < 255) && (t < 255);
    const float cr = valid ? cosp[h*256 + t + 257] : 0.0f;
    float lv[16], rv[16];
    float mL = 0.0f, mR = 0.0f;
#pragma unroll
    for(int l = 0; l < 16; ++l){
      float dl = cl - q[l];
      float Lv = __expf(-32.0f * dl * dl);
      float dr = cr - q[l];
      float Rv = valid ? __expf(-32.0f * dr * dr) : 0.0f;
      lv[l] = Lv; rv[l] = Rv;
      mL = fmaxf(mL, Lv); mR = fmaxf(mR, Rv);
    }
    mp = fmaxf(mp, mL * mR);
    float4* Lp = (float4*)&Lsh[t * 20];
    float4* Rp = (float4*)&Rsh[t * 20];
#pragma unroll
    for(int k = 0; k < 4; ++k){
      Lp[k] = make_float4(lv[4*k], lv[4*k+1], lv[4*k+2], lv[4*k+3]);
      Rp[k] = make_float4(rv[4*k], rv[4*k+1], rv[4*k+2], rv[4*k+3]);
    }
    __syncthreads();
#pragma unroll 4
    for(int it = 0; it < 16; ++it){
      const int p = it * 16 + g;
      const float4 Lx = *(const float4*)&Lsh[p*20 + i0];
      const float4 Rx = *(const float4*)&Rsh[p*20 + j0];
      const float lf[4] = {Lx.x, Lx.y, Lx.z, Lx.w};
      const float rf[4] = {Rx.x, Rx.y, Rx.z, Rx.w};
#pragma unroll
      for(int a = 0; a < 4; ++a)
#pragma unroll
        for(int bb = 0; bb < 4; ++bb) acc[a][bb] += lf[a] * rf[bb];
    }
    __syncthreads();
  }
#pragma unroll
  for(int a = 0; a < 4; ++a)
#pragma unroll
    for(int bb = 0; bb < 4; ++bb)
      Lsh[t*16 + a*4 + bb] = acc[a][bb];
  __syncthreads();
  const int i = t >> 4, j = t & 15;
  const int mm = ((i >> 2) << 2) + (j >> 2);
  const int idx = mm*16 + (i & 3)*4 + (j & 3);
  float v = 0.0f;
#pragma unroll
  for(int gg = 0; gg < 16; ++gg) v += Lsh[gg*256 + idx];
  ws[W_GP + b*256 + t] = v;

  mp = wrMax(mp);
  if((t & 63) == 0) smem[10240 + (t >> 6)] = mp;
  __syncthreads();
  if(t == 0)
    ws[W_CMXP + b] = fmaxf(fmaxf(smem[10240],smem[10241]),fmaxf(smem[10242],smem[10243]));
}

// ================= K4: sta + f1 + f2 + o1 conv + BN1 partials (NO atomics) =================
__global__ __launch_bounds__(256)
void k_mlp1(const float* __restrict__ f1w, const float* __restrict__ f1b,
            const float* __restrict__ f2w, const float* __restrict__ f2b,
            const float* __restrict__ o1b,
            float* __restrict__ ws)
{
  __shared__ __align__(16) float smem[10496];
  const int t = threadIdx.x, b = blockIdx.x;
  const int n = b >> 6, pos0 = (b & 63) << 2;

  // stage f2w^T (stride 129, float4 loads), f1 weights, scalars, mu partials, GP columns
#pragma unroll
  for(int k = 0; k < 8; ++k){
    float4 v = ((const float4*)f2w)[k*256 + t];
    int e = (k*256 + t)*4;
    int ch = e >> 6, c = e & 63;
    smem[(c+0)*129 + ch] = v.x;
    smem[(c+1)*129 + ch] = v.y;
    smem[(c+2)*129 + ch] = v.z;
    smem[(c+3)*129 + ch] = v.w;
  }
  if(t < 192) smem[8256 + t] = f1w[t];
  if(t < 64)  smem[8448 + t] = f1b[t];
  {
    float m2 = fmaxf(ws[W_CMXP + t], ws[W_CMXP + 256 + t]);
    m2 = wrMax(m2);
    if((t & 63) == 0) smem[9536 + (t >> 6)] = m2;
  }
  {
    float lo = (t < 128) ? ws[W_LOP + n*128 + t] : 1e30f;
    float hi = (t < 128) ? ws[W_HIP + n*128 + t] : -1e30f;
    lo = wrMin(lo); hi = wrMax(hi);
    if((t & 63) == 0){ smem[9540 + (t>>6)] = lo; smem[9544 + (t>>6)] = hi; }
  }
  smem[10112 + t] = ws[W_MUP2 + n*256 + t];    // this sample's 256 mu partials
  if(t < 128){
    float4 gp = *(const float4*)(ws + W_GP + (n*128 + t)*256 + pos0);
    smem[9600 + t]        = gp.x;
    smem[9600 + 128 + t]  = gp.y;
    smem[9600 + 256 + t]  = gp.z;
    smem[9600 + 384 + t]  = gp.w;
  }
  __syncthreads();
  if(t < 16){
    float m = 0.0f;
#pragma unroll
    for(int q = 0; q < 16; ++q) m += smem[10112 + t*16 + q];
    smem[9552 + t] = m * (1.0f/65536.0f);      // xav[c]; read 2 syncs later
  }
  const float comax = fmaxf(fmaxf(smem[9536],smem[9537]),fmaxf(smem[9538],smem[9539]));
  const float cmin  = fminf(fminf(smem[9540],smem[9541]),fminf(smem[9542],smem[9543]));
  const float cmax  = fmaxf(fmaxf(smem[9544],smem[9545]),fmaxf(smem[9546],smem[9547]));
  const float dqv   = cmax - cmin;
  const int w = t >> 6, j = t & 63;
  const int pos = pos0 + w;
  float gv = smem[9600 + w*128 + j] + smem[9600 + w*128 + 64 + j];
  gv = wrSumX(gv);
  const float sta = gv / (comax + 1e-6f);
  const int l1 = pos >> 4, l2 = pos & 15;
  const float ft0 = (float)(2*l2+1)*(1.0f/32.0f)*dqv + cmin;
  const float ft1 = (float)(2*l1+1)*(1.0f/32.0f)*dqv + cmin;
  float a = smem[8256+3*j]*ft0 + smem[8256+3*j+1]*ft1 + smem[8256+3*j+2]*sta + smem[8448+j];
  smem[8512 + w*64 + j] = (a > 0.0f) ? a : 0.01f*a;
  __syncthreads();
  // f2 (relu) -> h2 in smem [ch][w] stride 6
  {
    float acc0 = f2b[j], acc1 = f2b[j+64];
    const float* h1p = &smem[8512 + w*64];
#pragma unroll
    for(int c = 0; c < 64; ++c){
      float hv = h1p[c];
      acc0 += smem[c*129 + j]      * hv;
      acc1 += smem[c*129 + j + 64] * hv;
    }
    acc0 = fmaxf(acc0, 0.0f); acc1 = fmaxf(acc1, 0.0f);
    smem[8768 + j*6 + w]      = acc0;
    smem[8768 + (j+64)*6 + w] = acc1;
  }
  __syncthreads();
  // o1 conv: weight loaded ONCE, 2 FMAs per load (halved latency chain)
  {
    const int ch = t & 127, w2 = t >> 7;
    const int wwA = w2*2, wwB = w2*2 + 1;
    float base = o1b[ch];
#pragma unroll
    for(int c = 0; c < 16; ++c) base += ws[W_O1T + c*128 + ch] * smem[9552 + c];
    float vA = base, vB = base;
#pragma unroll 8
    for(int c = 0; c < 128; ++c){
      float wv = ws[W_O1T + (16 + c)*128 + ch];
      vA += wv * smem[8768 + c*6 + wwA];
      vB += wv * smem[8768 + c*6 + wwB];
    }
    smem[9600 + ch*4 + wwA] = vA;
    smem[9600 + ch*4 + wwB] = vB;
  }
  __syncthreads();
  // RAW write TRANSPOSED [n][pos][ch] (coalesced), 2 elems/thread
  {
    const int ch = t & 127, k = t >> 7;          // k in {0,1}
    ws[W_RAW + n*32768 + (pos0+k)*128 + ch]   = smem[9600 + ch*4 + k];
    ws[W_RAW + n*32768 + (pos0+k+2)*128 + ch] = smem[9600 + ch*4 + k+2];
  }
  // BN1 partials TRANSPOSED [row][block]: row t<128 = S(ch), row 128+t = S2(ch)
  if(t < 128){
    float v0 = smem[9600 + t*4], v1 = smem[9600 + t*4 + 1];
    float v2 = smem[9600 + t*4 + 2], v3 = smem[9600 + t*4 + 3];
    ws[W_BN1P + t*256 + b]         = (v0+v1)+(v2+v3);
    ws[W_BN1P + (128+t)*256 + b]   = (v0*v0+v1*v1)+(v2*v2+v3*v3);
  }
}

// ================= K5: BN1 finalize (row-contiguous) + o2 conv + BN2 partials =================
__global__ __launch_bounds__(256)
void k_mlp2(const float* __restrict__ o2b,
            const float* __restrict__ g1, const float* __restrict__ b1,
            float* __restrict__ ws)
{
  __shared__ float col[256];
  __shared__ __align__(16) float scsh[256];
  __shared__ __align__(16) float h3s[512];
  __shared__ __align__(16) float o2s[512];
  const int t = threadIdx.x, b = blockIdx.x;
  const int n = b >> 6, pos0 = (b & 63) << 2;

  // redundant per-block BN1 finalize: row t is CONTIGUOUS 256 floats -> 64 float4, full unroll
  {
    const float4* rp = (const float4*)(ws + W_BN1P + t*256);
    float4 a4 = make_float4(0.f,0.f,0.f,0.f);
#pragma unroll
    for(int k = 0; k < 64; ++k){
      float4 v = rp[k];
      a4.x += v.x; a4.y += v.y; a4.z += v.z; a4.w += v.w;
    }
    col[t] = (a4.x+a4.y)+(a4.z+a4.w);
  }
  __syncthreads();
  if(t < 128){
    float S = col[t], S2 = col[128 + t];
    float mean = S * (1.0f/1024.0f);
    float var  = S2 * (1.0f/1024.0f) - mean*mean;
    float sc = g1[t] * rsqrtf(var + 1e-5f);
    scsh[t]       = sc;
    scsh[128 + t] = b1[t] - mean*sc;
  }
  __syncthreads();
  // coalesced RAW [n][pos][ch] load + BN1 apply + relu -> h3s[ch*4+pos]
  {
    const int ch = t & 127, k = t >> 7;          // k in {0,1}
    float sc = scsh[ch], sh = scsh[128 + ch];
    float r0 = ws[W_RAW + n*32768 + (pos0+k)*128 + ch];
    float r1 = ws[W_RAW + n*32768 + (pos0+k+2)*128 + ch];
    h3s[ch*4 + k]   = fmaxf(r0*sc + sh, 0.0f);
    h3s[ch*4 + k+2] = fmaxf(r1*sc + sh, 0.0f);
  }
  __syncthreads();
  // o2 conv: weight loaded ONCE, 2 FMAs per load
  {
    const int ch = t & 127, w2 = t >> 7;
    const int wwA = w2*2, wwB = w2*2 + 1;
    float vA = o2b[ch], vB = vA;
#pragma unroll 8
    for(int c = 0; c < 128; ++c){
      float wv = ws[W_O2T + c*128 + ch];
      vA += wv * h3s[c*4 + wwA];
      vB += wv * h3s[c*4 + wwB];
    }
    o2s[ch*4 + wwA] = vA;
    o2s[ch*4 + wwB] = vB;
  }
  __syncthreads();
  // BN2 partials TRANSPOSED [row][block]: row ch = A, row 128+ch = S2
  if(t < 128){
    float a0 = o2s[t*4], a1 = o2s[t*4+1], a2 = o2s[t*4+2], a3 = o2s[t*4+3];
    ws[W_BN2P + t*256 + b]       = (a0+a1)+(a2+a3);
    ws[W_BN2P + (128+t)*256 + b] = (a0*a0+a1*a1)+(a2*a2+a3*a3);
  }
}

// ================= K6: BN2 finalize + threshold/redistribute/normalize (1 block) =============
__global__ __launch_bounds__(256)
void k_fin(const float* __restrict__ g2, const float* __restrict__ b2,
           float* __restrict__ ws, float* __restrict__ out)
{
  __shared__ __align__(16) float sS[512];
  __shared__ float s2S[128];
  __shared__ float red[16];
  const int t = threadIdx.x;

  // rows are contiguous: t<128 -> A-row ch=t (4 per-n segments of 64); t>=128 -> S2-row
  {
    const float4* rp = (const float4*)(ws + W_BN2P + t*256);
    if(t < 128){
#pragma unroll
      for(int nn = 0; nn < 4; ++nn){
        float4 a4 = make_float4(0.f,0.f,0.f,0.f);
#pragma unroll
        for(int k = 0; k < 16; ++k){
          float4 v = rp[nn*16 + k];
          a4.x += v.x; a4.y += v.y; a4.z += v.z; a4.w += v.w;
        }
        sS[nn*128 + t] = (a4.x+a4.y)+(a4.z+a4.w);
      }
    }else{
      float4 a4 = make_float4(0.f,0.f,0.f,0.f);
#pragma unroll
      for(int k = 0; k < 64; ++k){
        float4 v = rp[k];
        a4.x += v.x; a4.y += v.y; a4.z += v.z; a4.w += v.w;
      }
      s2S[t - 128] = (a4.x+a4.y)+(a4.z+a4.w);
    }
  }
  __syncthreads();
  if(t < 128){
    float S = ((sS[t] + sS[128+t]) + (sS[256+t] + sS[384+t]));
    float S2 = s2S[t];
    float mean = S * (1.0f/1024.0f);
    float var  = S2 * (1.0f/1024.0f) - mean*mean;
    float sc = g2[t] * rsqrtf(var + 1e-5f);
    float sh = b2[t] - mean*sc;
#pragma unroll
    for(int nn = 0; nn < 4; ++nn)
      sS[nn*128 + t] = sS[nn*128 + t]*(1.0f/256.0f)*sc + sh;
  }
  __syncthreads();
  float v0 = sS[t], v1 = sS[256 + t];
  float m = fmaxf(v0, v1);
  m = wrMax(m);
  if((t & 63) == 0) red[t>>6] = m;
  __syncthreads();
  const float mx = fmaxf(fmaxf(red[0],red[1]),fmaxf(red[2],red[3]));
  const float thr = 0.5f * mx;      // THETA = 0.5
  float e = fmaxf(v0 - thr, 0.0f) + fmaxf(v1 - thr, 0.0f);
  e = wrSum(e);
  if((t & 63) == 0) red[4 + (t>>6)] = e;
  __syncthreads();
  const float r = (red[4]+red[5]+red[6]+red[7]) * (1.0f/16.0f);  // extra / L
  const float d0 = (v0 > thr) ? (thr + r) : (v0 + r);
  const float d1 = (v1 > thr) ? (thr + r) : (v1 + r);
  float dn = fminf(d0, d1), dx = fmaxf(d0, d1);
  dn = wrMin(dn); dx = wrMax(dx);
  if((t & 63) == 0){ red[8 + (t>>6)] = dn; red[12 + (t>>6)] = dx; }
  __syncthreads();
  const float DN = fminf(fminf(red[8],red[9]),fminf(red[10],red[11]));
  const float DX = fmaxf(fmaxf(red[12],red[13]),fmaxf(red[14],red[15]));
  const float inv = 1.0f / (DX - DN + 1e-6f);
  out[t]       = (d0 - DN) * inv;
  out[256 + t] = (d1 - DN) * inv;
}

extern "C" void kernel_launch(void* const* d_in, const int* in_sizes, int n_in,
                              void* d_out, int out_size, void* d_ws, size_t ws_size,
                              hipStream_t stream){
  (void)in_sizes; (void)n_in; (void)out_size; (void)ws_size;
  const float* x   = (const float*)d_in[0];
  const float* f1w = (const float*)d_in[1];
  const float* f1b = (const float*)d_in[2];
  const float* f2w = (const float*)d_in[3];
  const float* f2b = (const float*)d_in[4];
  const float* o1w = (const float*)d_in[5];
  const float* o1b = (const float*)d_in[6];
  const float* g1  = (const float*)d_in[7];
  const float* b1  = (const float*)d_in[8];
  const float* o2w = (const float*)d_in[9];
  const float* o2b = (const float*)d_in[10];
  const float* g2  = (const float*)d_in[11];
  const float* b2  = (const float*)d_in[12];
  float* ws  = (float*)d_ws;
  float* out = (float*)d_out;

  k_mu  <<<1058, 256, 0, stream>>>(x, o1w, o2w, ws);
  k_cos <<<512,  256, 0, stream>>>(x, ws);
  k_gram<<<512,  256, 0, stream>>>(ws);
  k_mlp1<<<256,  256, 0, stream>>>(f1w, f1b, f2w, f2b, o1b, ws);
  k_mlp2<<<256,  256, 0, stream>>>(o2b, g1, b1, ws);
  k_fin <<<1,    256, 0, stream>>>(g2, b2, ws, out);
}

// Round 16
// 62.565 us; speedup vs baseline: 1.0326x; 1.0326x over previous
//
#include <hip/hip_runtime.h>
#include <math.h>

// ---------------- ws layout (float indices) ----------------
// NOTE: BN1P/BN2P are PER-BLOCK CONTIGUOUS (each block owns its own cache
// lines). The [row][block]-transposed variant interleaves 4B writes from 16
// blocks (= multiple XCDs) per 64B line and showed flaky post-timing
// divergence (r15) — cross-XCD L2 writeback clobbering. Do not transpose.
#define W_MUP2  0                       // 1024: per-(n,c,q) quarter-plane sums
#define W_LOP   1024                    // 512 cos-min partials (n*128+bb)
#define W_HIP   2048                    // 512 cos-max partials
#define W_CMXP  3072                    // 512 co-max partials
#define W_O1T   3840                    // 144*128 transposed o1w
#define W_O2T   22272                   // 128*128 transposed o2w
#define W_COS   38912                   // 4*65536
#define W_GP    (W_COS + 262144)        // 512 blocks * 256 gram partials
#define W_RAW   (W_GP + 131072)         // 4 * [pos(256)][ch(128)] o1 pre-BN (row-private per block)
#define W_BN1P  (W_RAW + 131072)        // 256 blocks * 256 (S | S2), per-block contiguous
#define W_BN2P  (W_BN1P + 65536)        // 256 blocks * 256 (A | S2), per-block contiguous

// ---------------- wave-64 reductions ----------------
__device__ __forceinline__ float wrSum(float v){
#pragma unroll
  for(int o = 32; o > 0; o >>= 1) v += __shfl_down(v, o, 64);
  return v;
}
__device__ __forceinline__ float wrSumX(float v){
#pragma unroll
  for(int o = 32; o > 0; o >>= 1) v += __shfl_xor(v, o, 64);
  return v;
}
__device__ __forceinline__ float wrMax(float v){
#pragma unroll
  for(int o = 32; o > 0; o >>= 1) v = fmaxf(v, __shfl_down(v, o, 64));
  return v;
}
__device__ __forceinline__ float wrMin(float v){
#pragma unroll
  for(int o = 32; o > 0; o >>= 1) v = fminf(v, __shfl_down(v, o, 64));
  return v;
}

// ================= K1: mu partials (x pass 1, 1024 blks) + weight transposes =================
__global__ __launch_bounds__(256)
void k_mu(const float* __restrict__ x, const float* __restrict__ o1w,
          const float* __restrict__ o2w, float* __restrict__ ws){
  const int t = threadIdx.x, b = blockIdx.x;
  if(b < 1024){
    __shared__ float red[4];
    const float4* xb = (const float4*)(x + b*4096);
    float4 v0 = xb[t], v1 = xb[t+256], v2 = xb[t+512], v3 = xb[t+768];
    float s = ((v0.x+v0.y)+(v0.z+v0.w)) + ((v1.x+v1.y)+(v1.z+v1.w))
            + ((v2.x+v2.y)+(v2.z+v2.w)) + ((v3.x+v3.y)+(v3.z+v3.w));
    s = wrSum(s);
    if((t & 63) == 0) red[t>>6] = s;
    __syncthreads();
    if(t == 0) ws[W_MUP2 + b] = (red[0]+red[1])+(red[2]+red[3]);
  } else if(b < 1042){
    const int c0 = (b - 1024)*8;
#pragma unroll
    for(int j = 0; j < 4; ++j){
      int idx = t + j*256;
      int ch = idx & 127, c = c0 + (idx >> 7);
      if(c < 144) ws[W_O1T + c*128 + ch] = o1w[ch*144 + c];
    }
  } else {
    const int c0 = (b - 1042)*8;
#pragma unroll
    for(int j = 0; j < 4; ++j){
      int idx = t + j*256;
      int ch = idx & 127, c = c0 + (idx >> 7);
      ws[W_O2T + c*128 + ch] = o2w[ch*128 + c];
    }
  }
}

// ================= K2: cos field (x pass 2, 512 blks, 2 px/thread float2) =================
__global__ __launch_bounds__(256)
void k_cos(const float* __restrict__ x, float* __restrict__ ws){
  __shared__ float sp[256];
  __shared__ float mu[16];
  __shared__ float red[8];
  const int t = threadIdx.x, b = blockIdx.x;
  const int n = b >> 7, bb = b & 127;
  sp[t] = ws[W_MUP2 + n*256 + t];
  __syncthreads();
  if(t < 16){
    float m = 0.0f;
#pragma unroll
    for(int q = 0; q < 16; ++q) m += sp[t*16 + q];
    mu[t] = m * (1.0f/65536.0f);
  }
  __syncthreads();
  float nn = 0.0f;
#pragma unroll
  for(int c = 0; c < 16; ++c) nn += mu[c]*mu[c];
  const float inv = 1.0f / fmaxf(sqrtf(nn), 1e-12f);
  const float2* xp = (const float2*)(x + n*1048576 + bb*512) + t;
  float dot0 = 0.0f, xx0 = 0.0f, dot1 = 0.0f, xx1 = 0.0f;
#pragma unroll
  for(int c = 0; c < 16; ++c){
    float2 v = xp[c*32768];
    dot0 += v.x*mu[c]; xx0 += v.x*v.x;
    dot1 += v.y*mu[c]; xx1 += v.y*v.y;
  }
  const float cv0 = dot0 * inv / fmaxf(sqrtf(xx0), 1e-12f);
  const float cv1 = dot1 * inv / fmaxf(sqrtf(xx1), 1e-12f);
  *(float2*)(ws + W_COS + n*65536 + bb*512 + 2*t) = make_float2(cv0, cv1);
  float lo = wrMin(fminf(cv0, cv1)), hi = wrMax(fmaxf(cv0, cv1));
  if((t & 63) == 0){ red[t>>6] = lo; red[4 + (t>>6)] = hi; }
  __syncthreads();
  if(t == 0){
    ws[W_LOP + n*128 + bb] = fminf(fminf(red[0],red[1]),fminf(red[2],red[3]));
    ws[W_HIP + n*128 + bb] = fmaxf(fmaxf(red[4],red[5]),fmaxf(red[6],red[7]));
  }
}

// ================= K3: quant + Gram partials + co-max partials (512 blks x 2 rows) ==========
__global__ __launch_bounds__(256) void k_gram(float* __restrict__ ws){
  __shared__ __align__(16) float smem[10256];
  float* Lsh = smem;            // 5120
  float* Rsh = smem + 5120;     // 5120
  const int t = threadIdx.x, b = blockIdx.x;
  const int n = b >> 7, h0 = (b & 127) << 1;       // 2 rows per block
  {
    float lo = (t < 128) ? ws[W_LOP + n*128 + t] : 1e30f;
    float hi = (t < 128) ? ws[W_HIP + n*128 + t] : -1e30f;
    lo = wrMin(lo); hi = wrMax(hi);
    if((t & 63) == 0){ smem[10240 + (t>>6)] = lo; smem[10244 + (t>>6)] = hi; }
  }
  __syncthreads();
  const float cmin = fminf(fminf(smem[10240],smem[10241]),fminf(smem[10242],smem[10243]));
  const float cmax = fmaxf(fmaxf(smem[10244],smem[10245]),fmaxf(smem[10246],smem[10247]));
  const float dqv  = cmax - cmin;
  float q[16];
#pragma unroll
  for(int l = 0; l < 16; ++l) q[l] = (float)(2*l+1) * (1.0f/32.0f) * dqv + cmin;

  const int m  = t & 15;
  const int g  = t >> 4;
  const int i0 = (m >> 2) << 2;
  const int j0 = (m & 3) << 2;
  float acc[4][4] = {{0.0f}};
  float mp = 0.0f;
  const float* cosp = ws + W_COS + n*65536;

  __syncthreads();
#pragma unroll
  for(int ch = 0; ch < 2; ++ch){
    const int h = h0 + ch;
    const float cl = cosp[h*256 + t];
    const bool valid = (h < 255) && (t < 255);
    const float cr = valid ? cosp[h*256 + t + 257] : 0.0f;
    float lv[16], rv[16];
    float mL = 0.0f, mR = 0.0f;
#pragma unroll
    for(int l = 0; l < 16; ++l){
      float dl = cl - q[l];
      float Lv = __expf(-32.0f * dl * dl);
      float dr = cr - q[l];
      float Rv = valid ? __expf(-32.0f * dr * dr) : 0.0f;
      lv[l] = Lv; rv[l] = Rv;
      mL = fmaxf(mL, Lv); mR = fmaxf(mR, Rv);
    }
    mp = fmaxf(mp, mL * mR);
    float4* Lp = (float4*)&Lsh[t * 20];
    float4* Rp = (float4*)&Rsh[t * 20];
#pragma unroll
    for(int k = 0; k < 4; ++k){
      Lp[k] = make_float4(lv[4*k], lv[4*k+1], lv[4*k+2], lv[4*k+3]);
      Rp[k] = make_float4(rv[4*k], rv[4*k+1], rv[4*k+2], rv[4*k+3]);
    }
    __syncthreads();
#pragma unroll 4
    for(int it = 0; it < 16; ++it){
      const int p = it * 16 + g;
      const float4 Lx = *(const float4*)&Lsh[p*20 + i0];
      const float4 Rx = *(const float4*)&Rsh[p*20 + j0];
      const float lf[4] = {Lx.x, Lx.y, Lx.z, Lx.w};
      const float rf[4] = {Rx.x, Rx.y, Rx.z, Rx.w};
#pragma unroll
      for(int a = 0; a < 4; ++a)
#pragma unroll
        for(int bb = 0; bb < 4; ++bb) acc[a][bb] += lf[a] * rf[bb];
    }
    __syncthreads();
  }
#pragma unroll
  for(int a = 0; a < 4; ++a)
#pragma unroll
    for(int bb = 0; bb < 4; ++bb)
      Lsh[t*16 + a*4 + bb] = acc[a][bb];
  __syncthreads();
  const int i = t >> 4, j = t & 15;
  const int mm = ((i >> 2) << 2) + (j >> 2);
  const int idx = mm*16 + (i & 3)*4 + (j & 3);
  float v = 0.0f;
#pragma unroll
  for(int gg = 0; gg < 16; ++gg) v += Lsh[gg*256 + idx];
  ws[W_GP + b*256 + t] = v;

  mp = wrMax(mp);
  if((t & 63) == 0) smem[10240 + (t >> 6)] = mp;
  __syncthreads();
  if(t == 0)
    ws[W_CMXP + b] = fmaxf(fmaxf(smem[10240],smem[10241]),fmaxf(smem[10242],smem[10243]));
}

// ================= K4: sta + f1 + f2 + o1 conv + BN1 partials (NO atomics) =================
__global__ __launch_bounds__(256)
void k_mlp1(const float* __restrict__ f1w, const float* __restrict__ f1b,
            const float* __restrict__ f2w, const float* __restrict__ f2b,
            const float* __restrict__ o1b,
            float* __restrict__ ws)
{
  __shared__ __align__(16) float smem[10496];
  const int t = threadIdx.x, b = blockIdx.x;
  const int n = b >> 6, pos0 = (b & 63) << 2;

  // stage f2w^T (stride 129, float4 loads), f1 weights, scalars, mu partials, GP columns
#pragma unroll
  for(int k = 0; k < 8; ++k){
    float4 v = ((const float4*)f2w)[k*256 + t];
    int e = (k*256 + t)*4;
    int ch = e >> 6, c = e & 63;
    smem[(c+0)*129 + ch] = v.x;
    smem[(c+1)*129 + ch] = v.y;
    smem[(c+2)*129 + ch] = v.z;
    smem[(c+3)*129 + ch] = v.w;
  }
  if(t < 192) smem[8256 + t] = f1w[t];
  if(t < 64)  smem[8448 + t] = f1b[t];
  {
    float m2 = fmaxf(ws[W_CMXP + t], ws[W_CMXP + 256 + t]);
    m2 = wrMax(m2);
    if((t & 63) == 0) smem[9536 + (t >> 6)] = m2;
  }
  {
    float lo = (t < 128) ? ws[W_LOP + n*128 + t] : 1e30f;
    float hi = (t < 128) ? ws[W_HIP + n*128 + t] : -1e30f;
    lo = wrMin(lo); hi = wrMax(hi);
    if((t & 63) == 0){ smem[9540 + (t>>6)] = lo; smem[9544 + (t>>6)] = hi; }
  }
  smem[10112 + t] = ws[W_MUP2 + n*256 + t];    // this sample's 256 mu partials
  if(t < 128){
    float4 gp = *(const float4*)(ws + W_GP + (n*128 + t)*256 + pos0);
    smem[9600 + t]        = gp.x;
    smem[9600 + 128 + t]  = gp.y;
    smem[9600 + 256 + t]  = gp.z;
    smem[9600 + 384 + t]  = gp.w;
  }
  __syncthreads();
  if(t < 16){
    float m = 0.0f;
#pragma unroll
    for(int q = 0; q < 16; ++q) m += smem[10112 + t*16 + q];
    smem[9552 + t] = m * (1.0f/65536.0f);      // xav[c]; read 2 syncs later
  }
  const float comax = fmaxf(fmaxf(smem[9536],smem[9537]),fmaxf(smem[9538],smem[9539]));
  const float cmin  = fminf(fminf(smem[9540],smem[9541]),fminf(smem[9542],smem[9543]));
  const float cmax  = fmaxf(fmaxf(smem[9544],smem[9545]),fmaxf(smem[9546],smem[9547]));
  const float dqv   = cmax - cmin;
  const int w = t >> 6, j = t & 63;
  const int pos = pos0 + w;
  float gv = smem[9600 + w*128 + j] + smem[9600 + w*128 + 64 + j];
  gv = wrSumX(gv);
  const float sta = gv / (comax + 1e-6f);
  const int l1 = pos >> 4, l2 = pos & 15;
  const float ft0 = (float)(2*l2+1)*(1.0f/32.0f)*dqv + cmin;
  const float ft1 = (float)(2*l1+1)*(1.0f/32.0f)*dqv + cmin;
  float a = smem[8256+3*j]*ft0 + smem[8256+3*j+1]*ft1 + smem[8256+3*j+2]*sta + smem[8448+j];
  smem[8512 + w*64 + j] = (a > 0.0f) ? a : 0.01f*a;
  __syncthreads();
  // f2 (relu) -> h2 in smem [ch][w] stride 6
  {
    float acc0 = f2b[j], acc1 = f2b[j+64];
    const float* h1p = &smem[8512 + w*64];
#pragma unroll
    for(int c = 0; c < 64; ++c){
      float hv = h1p[c];
      acc0 += smem[c*129 + j]      * hv;
      acc1 += smem[c*129 + j + 64] * hv;
    }
    acc0 = fmaxf(acc0, 0.0f); acc1 = fmaxf(acc1, 0.0f);
    smem[8768 + j*6 + w]      = acc0;
    smem[8768 + (j+64)*6 + w] = acc1;
  }
  __syncthreads();
  // o1 conv with transposed weights (coalesced): thread (ch = t&127) x 2 positions
  {
    const int ch = t & 127, w2 = t >> 7;
    float base = o1b[ch];
#pragma unroll
    for(int c = 0; c < 16; ++c) base += ws[W_O1T + c*128 + ch] * smem[9552 + c];
#pragma unroll
    for(int k = 0; k < 2; ++k){
      const int ww = w2*2 + k;
      float v = base;
#pragma unroll 8
      for(int c = 0; c < 128; ++c) v += ws[W_O1T + (16 + c)*128 + ch] * smem[8768 + c*6 + ww];
      smem[9600 + ch*4 + ww] = v;
    }
  }
  __syncthreads();
  // RAW write TRANSPOSED [n][pos][ch] (coalesced; each 512B pos-row owned by one block)
  {
    const int ch = t & 127, k = t >> 7;          // k in {0,1}
    ws[W_RAW + n*32768 + (pos0+k)*128 + ch]   = smem[9600 + ch*4 + k];
    ws[W_RAW + n*32768 + (pos0+k+2)*128 + ch] = smem[9600 + ch*4 + k+2];
  }
  // BN1 partials PER-BLOCK CONTIGUOUS (line-private): [block][S(128) | S2(128)]
  if(t < 128){
    float v0 = smem[9600 + t*4], v1 = smem[9600 + t*4 + 1];
    float v2 = smem[9600 + t*4 + 2], v3 = smem[9600 + t*4 + 3];
    ws[W_BN1P + b*256 + t]       = (v0+v1)+(v2+v3);
    ws[W_BN1P + b*256 + 128 + t] = (v0*v0+v1*v1)+(v2*v2+v3*v3);
  }
}

// ================= K5: BN1 finalize (redundant/block) + o2 conv + BN2 partials =================
__global__ __launch_bounds__(256)
void k_mlp2(const float* __restrict__ o2b,
            const float* __restrict__ g1, const float* __restrict__ b1,
            float* __restrict__ ws)
{
  __shared__ float col[256];
  __shared__ __align__(16) float scsh[256];
  __shared__ __align__(16) float h3s[512];
  __shared__ __align__(16) float o2s[512];
  const int t = threadIdx.x, b = blockIdx.x;
  const int n = b >> 6, pos0 = (b & 63) << 2;

  // redundant per-block BN1 finalize (L2-resident strided column sums, 4-way ILP)
  {
    float a0 = 0.0f, a1 = 0.0f, a2 = 0.0f, a3 = 0.0f;
    for(int k = 0; k < 256; k += 4){
      a0 += ws[W_BN1P + (k+0)*256 + t];
      a1 += ws[W_BN1P + (k+1)*256 + t];
      a2 += ws[W_BN1P + (k+2)*256 + t];
      a3 += ws[W_BN1P + (k+3)*256 + t];
    }
    col[t] = (a0+a1)+(a2+a3);
  }
  __syncthreads();
  if(t < 128){
    float S = col[t], S2 = col[128 + t];
    float mean = S * (1.0f/1024.0f);
    float var  = S2 * (1.0f/1024.0f) - mean*mean;
    float sc = g1[t] * rsqrtf(var + 1e-5f);
    scsh[t]       = sc;
    scsh[128 + t] = b1[t] - mean*sc;
  }
  __syncthreads();
  // coalesced RAW [n][pos][ch] load + BN1 apply + relu -> h3s[ch*4+pos]
  {
    const int ch = t & 127, k = t >> 7;          // k in {0,1}
    float sc = scsh[ch], sh = scsh[128 + ch];
    float r0 = ws[W_RAW + n*32768 + (pos0+k)*128 + ch];
    float r1 = ws[W_RAW + n*32768 + (pos0+k+2)*128 + ch];
    h3s[ch*4 + k]   = fmaxf(r0*sc + sh, 0.0f);
    h3s[ch*4 + k+2] = fmaxf(r1*sc + sh, 0.0f);
  }
  __syncthreads();
  // o2 conv with transposed weights (coalesced): thread (ch) x 2 positions
  {
    const int ch = t & 127, w2 = t >> 7;
#pragma unroll
    for(int k = 0; k < 2; ++k){
      const int ww = w2*2 + k;
      float v = o2b[ch];
#pragma unroll 8
      for(int c = 0; c < 128; ++c) v += ws[W_O2T + c*128 + ch] * h3s[c*4 + ww];
      o2s[ch*4 + ww] = v;
    }
  }
  __syncthreads();
  // BN2 partials PER-BLOCK CONTIGUOUS (line-private): [block][A(128) | S2(128)]
  if(t < 128){
    float a0 = o2s[t*4], a1 = o2s[t*4+1], a2 = o2s[t*4+2], a3 = o2s[t*4+3];
    ws[W_BN2P + b*256 + t]       = (a0+a1)+(a2+a3);
    ws[W_BN2P + b*256 + 128 + t] = (a0*a0+a1*a1)+(a2*a2+a3*a3);
  }
}

// ================= K6: BN2 finalize + threshold/redistribute/normalize (1 block) =============
__global__ __launch_bounds__(256)
void k_fin(const float* __restrict__ g2, const float* __restrict__ b2,
           float* __restrict__ ws, float* __restrict__ out)
{
  __shared__ __align__(16) float sS[512];
  __shared__ float s2S[128];
  __shared__ float red[16];
  const int t = threadIdx.x;

  if(t < 128){
#pragma unroll
    for(int nn = 0; nn < 4; ++nn){
      float a = 0.0f;
      for(int k = 0; k < 64; ++k) a += ws[W_BN2P + (nn*64 + k)*256 + t];
      sS[nn*128 + t] = a;
    }
  }else{
    const int ch = t - 128;
    float a = 0.0f;
    for(int k = 0; k < 256; ++k) a += ws[W_BN2P + k*256 + 128 + ch];
    s2S[ch] = a;
  }
  __syncthreads();
  if(t < 128){
    float S = ((sS[t] + sS[128+t]) + (sS[256+t] + sS[384+t]));
    float S2 = s2S[t];
    float mean = S * (1.0f/1024.0f);
    float var  = S2 * (1.0f/1024.0f) - mean*mean;
    float sc = g2[t] * rsqrtf(var + 1e-5f);
    float sh = b2[t] - mean*sc;
#pragma unroll
    for(int nn = 0; nn < 4; ++nn)
      sS[nn*128 + t] = sS[nn*128 + t]*(1.0f/256.0f)*sc + sh;
  }
  __syncthreads();
  float v0 = sS[t], v1 = sS[256 + t];
  float m = fmaxf(v0, v1);
  m = wrMax(m);
  if((t & 63) == 0) red[t>>6] = m;
  __syncthreads();
  const float mx = fmaxf(fmaxf(red[0],red[1]),fmaxf(red[2],red[3]));
  const float thr = 0.5f * mx;      // THETA = 0.5
  float e = fmaxf(v0 - thr, 0.0f) + fmaxf(v1 - thr, 0.0f);
  e = wrSum(e);
  if((t & 63) == 0) red[4 + (t>>6)] = e;
  __syncthreads();
  const float r = (red[4]+red[5]+red[6]+red[7]) * (1.0f/16.0f);  // extra / L
  const float d0 = (v0 > thr) ? (thr + r) : (v0 + r);
  const float d1 = (v1 > thr) ? (thr + r) : (v1 + r);
  float dn = fminf(d0, d1), dx = fmaxf(d0, d1);
  dn = wrMin(dn); dx = wrMax(dx);
  if((t & 63) == 0){ red[8 + (t>>6)] = dn; red[12 + (t>>6)] = dx; }
  __syncthreads();
  const float DN = fminf(fminf(red[8],red[9]),fminf(red[10],red[11]));
  const float DX = fmaxf(fmaxf(red[12],red[13]),fmaxf(red[14],red[15]));
  const float inv = 1.0f / (DX - DN + 1e-6f);
  out[t]       = (d0 - DN) * inv;
  out[256 + t] = (d1 - DN) * inv;
}

extern "C" void kernel_launch(void* const* d_in, const int* in_sizes, int n_in,
                              void* d_out, int out_size, void* d_ws, size_t ws_size,
                              hipStream_t stream){
  (void)in_sizes; (void)n_in; (void)out_size; (void)ws_size;
  const float* x   = (const float*)d_in[0];
  const float* f1w = (const float*)d_in[1];
  const float* f1b = (const float*)d_in[2];
  const float* f2w = (const float*)d_in[3];
  const float* f2b = (const float*)d_in[4];
  const float* o1w = (const float*)d_in[5];
  const float* o1b = (const float*)d_in[6];
  const float* g1  = (const float*)d_in[7];
  const float* b1  = (const float*)d_in[8];
  const float* o2w = (const float*)d_in[9];
  const float* o2b = (const float*)d_in[10];
  const float* g2  = (const float*)d_in[11];
  const float* b2  = (const float*)d_in[12];
  float* ws  = (float*)d_ws;
  float* out = (float*)d_out;

  k_mu  <<<1058, 256, 0, stream>>>(x, o1w, o2w, ws);
  k_cos <<<512,  256, 0, stream>>>(x, ws);
  k_gram<<<512,  256, 0, stream>>>(ws);
  k_mlp1<<<256,  256, 0, stream>>>(f1w, f1b, f2w, f2b, o1b, ws);
  k_mlp2<<<256,  256, 0, stream>>>(o2b, g1, b1, ws);
  k_fin <<<1,    256, 0, stream>>>(g2, b2, ws, out);
}